// Round 12
// baseline (168.331 us; speedup 1.0000x reference)
//
#include <hip/hip_runtime.h>
#include <hip/hip_bf16.h>
#include <math.h>

#define EPSF 1e-8f
typedef __attribute__((ext_vector_type(8))) short short8;
typedef __attribute__((ext_vector_type(4))) float f32x4;

__device__ __forceinline__ float wred_sum(float v) {
#pragma unroll
  for (int o = 32; o > 0; o >>= 1) v += __shfl_down(v, o, 64);
  return v;
}

static __device__ __forceinline__ unsigned short f2bf(float f) {
  __hip_bfloat16 h = __float2bfloat16(f);
  return *reinterpret_cast<unsigned short*>(&h);
}
static __device__ __forceinline__ float bf2f(unsigned short u) {
  unsigned int v = ((unsigned int)u) << 16;
  float f;
  __builtin_memcpy(&f, &v, 4);
  return f;
}

// load 16 t-consecutive x values (fp32, guarded) -> 16 bf16 in two short8 regs
__device__ __forceinline__ void load_x16(const float* __restrict__ xr, int ts, int T,
                                         short8& lo, short8& hi) {
  unsigned short xb[16];
#pragma unroll
  for (int m = 0; m < 4; m++) {
    int t = ts + m * 4;
    float4 v;
    if (t + 3 < T) {
      v = *reinterpret_cast<const float4*>(&xr[t]);
    } else {
      v.x = (t < T) ? xr[t] : 0.f;
      v.y = (t + 1 < T) ? xr[t + 1] : 0.f;
      v.z = (t + 2 < T) ? xr[t + 2] : 0.f;
      v.w = (t + 3 < T) ? xr[t + 3] : 0.f;
    }
    xb[m * 4 + 0] = f2bf(v.x); xb[m * 4 + 1] = f2bf(v.y);
    xb[m * 4 + 2] = f2bf(v.z); xb[m * 4 + 3] = f2bf(v.w);
  }
  lo = *reinterpret_cast<short8*>(&xb[0]);
  hi = *reinterpret_cast<short8*>(&xb[8]);
}

// ---------------- K-1: zero the atomic accumulators
__global__ __launch_bounds__(256) void k_zero(float* __restrict__ p, int n4) {
  int i = blockIdx.x * 256 + threadIdx.x;
  if (i < n4)
    *reinterpret_cast<float4*>(p + (size_t)i * 4) = (float4){0.f, 0.f, 0.f, 0.f};
}

// ---------------- K0: weights -> bf16 (awb[d][c] from attn_w[:, :C]; cwb = ctx_w)
__global__ __launch_bounds__(256) void k_convert(
    const float* __restrict__ attn_w, const float* __restrict__ ctx_w,
    unsigned short* __restrict__ awb, unsigned short* __restrict__ cwb, int C, int D) {
  int i = blockIdx.x * 256 + threadIdx.x;
  int DC = D * C;
  if (i < DC) {
    int d = i / C, c = i % C;
    awb[i] = f2bf(attn_w[(size_t)d * 3 * C + c]);
  } else if (i < 2 * DC) {
    int j = i - DC;
    cwb[j] = f2bf(ctx_w[j]);
  }
}

// ---------------- K1: reduce-only masked partial sums (no LDS, no transpose)
__global__ __launch_bounds__(256) void k_ms(
    const float* __restrict__ x, const int* __restrict__ mask,
    float* __restrict__ sums, int C, int T) {
  int b = blockIdx.z, c0 = blockIdx.x * 64, t0 = blockIdx.y * 64;
  int tid = threadIdx.x;
  int row = tid >> 2, q = tid & 3;
  const float* xr = x + ((size_t)b * C + c0 + row) * T;
  const int* mr = mask + (size_t)b * T;
  float s1 = 0.f, s2 = 0.f;
#pragma unroll
  for (int m = 0; m < 4; m++) {
    int t = t0 + q * 16 + m * 4;
    float4 v;
    float mv[4];
    if (t + 3 < T) {
      v = *reinterpret_cast<const float4*>(&xr[t]);
      int4 mm = *reinterpret_cast<const int4*>(&mr[t]);
      mv[0] = (float)mm.x; mv[1] = (float)mm.y; mv[2] = (float)mm.z; mv[3] = (float)mm.w;
    } else {
      v.x = (t < T) ? xr[t] : 0.f;     mv[0] = (t < T) ? (float)mr[t] : 0.f;
      v.y = (t+1 < T) ? xr[t+1] : 0.f; mv[1] = (t+1 < T) ? (float)mr[t+1] : 0.f;
      v.z = (t+2 < T) ? xr[t+2] : 0.f; mv[2] = (t+2 < T) ? (float)mr[t+2] : 0.f;
      v.w = (t+3 < T) ? xr[t+3] : 0.f; mv[3] = (t+3 < T) ? (float)mr[t+3] : 0.f;
    }
    s1 += mv[0]*v.x + mv[1]*v.y + mv[2]*v.z + mv[3]*v.w;
    s2 += mv[0]*v.x*v.x + mv[1]*v.y*v.y + mv[2]*v.z*v.z + mv[3]*v.w*v.w;
  }
  s1 += __shfl_down(s1, 2, 4); s1 += __shfl_down(s1, 1, 4);
  s2 += __shfl_down(s2, 2, 4); s2 += __shfl_down(s2, 1, 4);
  if (q == 0) {
    float* sp = &sums[((size_t)b * C + c0 + row) * 2];
    atomicAdd(sp, s1);
    atomicAdd(sp + 1, s2);
  }
}

// ---------------- K1b: finalize mean/std from sums + mask lengths
__global__ __launch_bounds__(256) void k_ms_fin(
    const float* __restrict__ sums, const int* __restrict__ mask,
    float* __restrict__ mean, float* __restrict__ stdv, int C, int T) {
  int b = blockIdx.x;
  int tid = threadIdx.x;
  const int* mr = mask + (size_t)b * T;
  float sl = 0.f;
  for (int t = tid; t < T; t += 256) sl += (float)mr[t];
  __shared__ float rl[4];
  sl = wred_sum(sl);
  if ((tid & 63) == 0) rl[tid >> 6] = sl;
  __syncthreads();
  float L = fmaxf(rl[0] + rl[1] + rl[2] + rl[3], 1.f);
  for (int c = tid; c < C; c += 256) {
    float s1 = sums[((size_t)b * C + c) * 2];
    float s2 = sums[((size_t)b * C + c) * 2 + 1];
    float mu = s1 / L;
    float var = s2 / L - mu * mu;
    mean[(size_t)b * C + c] = mu;
    stdv[(size_t)b * C + c] = sqrtf(fmaxf(var, EPSF));
  }
}

// ---------------- K2: bias2[b,d] = attn_b[d] + w[d,C:2C].mean + w[d,2C:3C].std (fp32)
__global__ __launch_bounds__(256) void k_bias2(
    const float* __restrict__ attn_w, const float* __restrict__ attn_b,
    const float* __restrict__ mean, const float* __restrict__ stdv,
    float* __restrict__ bias2, int C, int D) {
  int bd = blockIdx.x;
  int b = bd / D;
  int d = bd % D;
  const float* wr = attn_w + (size_t)d * 3 * C;
  float s = 0.f;
  for (int c = threadIdx.x; c < C; c += 256)
    s += wr[C + c] * mean[(size_t)b * C + c] + wr[2 * C + c] * stdv[(size_t)b * C + c];
  __shared__ float r[4];
  s = wred_sum(s);
  if ((threadIdx.x & 63) == 0) r[threadIdx.x >> 6] = s;
  __syncthreads();
  if (threadIdx.x == 0) bias2[bd] = attn_b[d] + r[0] + r[1] + r[2] + r[3];
}

// ---------------- K3: MFMA GEMM1 reading x DIRECTLY (xbT eliminated).
// 64t x 128d tile per block. Per 64-c chunk: load x fp32 (coalesced along t,
// L3-hot), cvt to bf16 in regs, stage Xf[c][t], transpose in LDS -> As[t][c],
// stage awb -> Bs, MFMA. Register prefetch of chunk k+1. 3 barriers/chunk.
__global__ __launch_bounds__(256) void k_gemm1x(
    const float* __restrict__ x, const unsigned short* __restrict__ awb,
    const float* __restrict__ bias2, unsigned short* __restrict__ alphaT,
    int C, int T, int D) {
  int b = blockIdx.y;
  int t0 = blockIdx.x * 64;
  int tid = threadIdx.x;
  int w = tid >> 6, lane = tid & 63;
  int l15 = lane & 15, g = lane >> 4;
  __shared__ unsigned short Xf[64][72];   // x chunk [c-local][t-local] bf16
  __shared__ unsigned short As[64][72];   // transposed [t-local][c-local]
  __shared__ unsigned short Bs[128][72];  // awb chunk [d][c-local]

  f32x4 acc[4][2];
#pragma unroll
  for (int i = 0; i < 4; i++)
#pragma unroll
    for (int j = 0; j < 2; j++) acc[i][j] = (f32x4){0.f, 0.f, 0.f, 0.f};

  int cr = tid >> 2, q = tid & 3;  // Xf staging: c-row, t-quarter
  int dr = tid >> 1, h = tid & 1;  // Bs staging: d-row, c-half

  // prefetch chunk 0
  short8 rx0, rx1, rb[4];
  load_x16(x + ((size_t)b * C + cr) * T, t0 + q * 16, T, rx0, rx1);
#pragma unroll
  for (int qq = 0; qq < 4; qq++)
    rb[qq] = *reinterpret_cast<const short8*>(&awb[(size_t)dr * C + h * 32 + qq * 8]);

  for (int c0 = 0; c0 < C; c0 += 64) {
    __syncthreads();  // B1: prev MFMA done reading As/Bs; prev transpose done reading Xf
    *reinterpret_cast<short8*>(&Xf[cr][q * 16]) = rx0;
    *reinterpret_cast<short8*>(&Xf[cr][q * 16 + 8]) = rx1;
#pragma unroll
    for (int qq = 0; qq < 4; qq++)
      *reinterpret_cast<short8*>(&Bs[dr][h * 32 + qq * 8]) = rb[qq];
    if (c0 + 64 < C) {
      load_x16(x + ((size_t)b * C + c0 + 64 + cr) * T, t0 + q * 16, T, rx0, rx1);
      size_t nB = (size_t)dr * C + c0 + 64 + h * 32;
#pragma unroll
      for (int qq = 0; qq < 4; qq++)
        rb[qq] = *reinterpret_cast<const short8*>(&awb[nB + qq * 8]);
    }
    __syncthreads();  // B2: Xf, Bs visible
    {
      unsigned short buf[16];
#pragma unroll
      for (int m = 0; m < 16; m++) buf[m] = Xf[q * 16 + m][cr];
      *reinterpret_cast<short8*>(&As[cr][q * 16]) = *reinterpret_cast<short8*>(&buf[0]);
      *reinterpret_cast<short8*>(&As[cr][q * 16 + 8]) = *reinterpret_cast<short8*>(&buf[8]);
    }
    __syncthreads();  // B3: As visible
#pragma unroll
    for (int ks = 0; ks < 2; ks++) {
      short8 a[4], bb[2];
#pragma unroll
      for (int tf = 0; tf < 4; tf++)
        a[tf] = *reinterpret_cast<const short8*>(&As[tf * 16 + l15][ks * 32 + g * 8]);
#pragma unroll
      for (int df = 0; df < 2; df++)
        bb[df] = *reinterpret_cast<const short8*>(&Bs[w * 32 + df * 16 + l15][ks * 32 + g * 8]);
#pragma unroll
      for (int tf = 0; tf < 4; tf++)
#pragma unroll
        for (int df = 0; df < 2; df++)
          acc[tf][df] = __builtin_amdgcn_mfma_f32_16x16x32_bf16(a[tf], bb[df], acc[tf][df], 0, 0, 0);
    }
  }
#pragma unroll
  for (int df = 0; df < 2; df++) {
    int d = w * 32 + df * 16 + l15;
    float bias = bias2[(size_t)b * D + d];
#pragma unroll
    for (int tf = 0; tf < 4; tf++)
#pragma unroll
      for (int r = 0; r < 4; r++) {
        int t = t0 + tf * 16 + g * 4 + r;
        if (t < T)
          alphaT[((size_t)b * T + t) * D + d] = f2bf(tanhf(bias + acc[tf][df][r]));
      }
  }
}

// ---------------- K4: fused MFMA GEMM2 + masked exp + partial pooled sums
// r11's depth-2 pipeline (Bl dbuf + reg prefetch k+2), but x values staged
// from x fp32 directly (L3-hot; xbT is gone): float4 load -> cvt -> bf16
// Xf[c][t] tiles; xv reads are row-contiguous. ctx_b omitted (shift-invariance).
__global__ __launch_bounds__(256) void k_pool2(
    const unsigned short* __restrict__ alphaT, const unsigned short* __restrict__ cwb,
    const float* __restrict__ x, const int* __restrict__ mask,
    float* __restrict__ Sacc, int C, int T, int D) {
  int b = blockIdx.z;
  int c0 = blockIdx.y * 64;
  int ch0 = blockIdx.x * 256;
  int tid = threadIdx.x;
  int w = tid >> 6, lane = tid & 63, l15 = lane & 15, g = lane >> 4;
  __shared__ unsigned short Bl[2][64][136];  // alphaT tiles [t][d]
  __shared__ unsigned short Xf[2][64][72];   // x tiles [c-local][t-local] bf16

  short8 a[4];
#pragma unroll
  for (int ks = 0; ks < 4; ks++)
    a[ks] = *reinterpret_cast<const short8*>(
        &cwb[(size_t)(c0 + w * 16 + l15) * D + ks * 32 + g * 8]);
  int cbase = c0 + w * 16 + g * 4;
  float S0[4] = {0.f, 0.f, 0.f, 0.f};
  float S1[4] = {0.f, 0.f, 0.f, 0.f};
  float S2[4] = {0.f, 0.f, 0.f, 0.f};

  const int* mr = mask + (size_t)b * T;
  int srow = tid >> 2, sq = tid & 3;
  const float* xrc = x + ((size_t)b * C + c0 + srow) * T;  // srow = c-row for Xf

  int rem = T - ch0;
  int ntt = rem >= 256 ? 4 : (rem + 63) >> 6;

  short8 pa0, pa1, pa2, pa3, px0, px1;

#define LOADSUB(st)                                                            \
  {                                                                            \
    int trow = ch0 + (st) * 64 + srow;                                         \
    pa0 = pa1 = pa2 = pa3 = (short8){};                                        \
    if (trow < T) {                                                            \
      const unsigned short* sa = &alphaT[((size_t)b * T + trow) * D + sq * 32];\
      pa0 = *reinterpret_cast<const short8*>(sa);                              \
      pa1 = *reinterpret_cast<const short8*>(sa + 8);                          \
      pa2 = *reinterpret_cast<const short8*>(sa + 16);                         \
      pa3 = *reinterpret_cast<const short8*>(sa + 24);                         \
    }                                                                          \
    load_x16(xrc, ch0 + (st) * 64 + sq * 16, T, px0, px1);                     \
  }

#define WRITESUB(bufi)                                                         \
  {                                                                            \
    *reinterpret_cast<short8*>(&Bl[bufi][srow][sq * 32]) = pa0;                \
    *reinterpret_cast<short8*>(&Bl[bufi][srow][sq * 32 + 8]) = pa1;            \
    *reinterpret_cast<short8*>(&Bl[bufi][srow][sq * 32 + 16]) = pa2;           \
    *reinterpret_cast<short8*>(&Bl[bufi][srow][sq * 32 + 24]) = pa3;           \
    *reinterpret_cast<short8*>(&Xf[bufi][srow][sq * 16]) = px0;                \
    *reinterpret_cast<short8*>(&Xf[bufi][srow][sq * 16 + 8]) = px1;            \
  }

  // prologue: buf0 <- subtile 0; regs <- subtile 1
  LOADSUB(0);
  WRITESUB(0);
  if (ntt > 1) LOADSUB(1);
  __syncthreads();

  for (int k = 0; k < ntt; k++) {
    int buf = k & 1;
    if (k + 1 < ntt) {
      WRITESUB((k + 1) & 1);
      if (k + 2 < ntt) LOADSUB(k + 2);
    }
    int t0 = ch0 + k * 64;
#pragma unroll
    for (int tf = 0; tf < 4; tf++) {
      f32x4 p = (f32x4){0.f, 0.f, 0.f, 0.f};
#pragma unroll
      for (int ks = 0; ks < 4; ks++) {
        short8 bb = *reinterpret_cast<const short8*>(
            &Bl[buf][tf * 16 + l15][ks * 32 + g * 8]);
        p = __builtin_amdgcn_mfma_f32_16x16x32_bf16(a[ks], bb, p, 0, 0, 0);
      }
      int t = t0 + tf * 16 + l15;
      bool valid = (t < T) && (mr[t < T ? t : 0] != 0);
#pragma unroll
      for (int r = 0; r < 4; r++) {
        float e = valid ? __expf(p[r]) : 0.f;  // logits tanh-bounded: no max-sub
        float xv = bf2f(Xf[buf][w * 16 + g * 4 + r][tf * 16 + l15]);
        S0[r] += e; S1[r] += e * xv; S2[r] += e * xv * xv;
      }
    }
    __syncthreads();
  }
#undef LOADSUB
#undef WRITESUB

#pragma unroll
  for (int r = 0; r < 4; r++) {
#pragma unroll
    for (int o = 1; o < 16; o <<= 1) {
      S0[r] += __shfl_xor(S0[r], o, 16);
      S1[r] += __shfl_xor(S1[r], o, 16);
      S2[r] += __shfl_xor(S2[r], o, 16);
    }
  }
  if (l15 == 0) {
#pragma unroll
    for (int r = 0; r < 4; r++) {
      float* sp = &Sacc[((size_t)b * C + cbase + r) * 3];
      atomicAdd(sp, S0[r]);
      atomicAdd(sp + 1, S1[r]);
      atomicAdd(sp + 2, S2[r]);
    }
  }
}

// ---------------- K5: finalize pooled mean/std
__global__ __launch_bounds__(256) void k_out(
    const float* __restrict__ Sacc, float* __restrict__ out, int C) {
  int b = blockIdx.x;
  for (int c = threadIdx.x; c < C; c += 256) {
    float S0 = Sacc[((size_t)b * C + c) * 3];
    float S1 = Sacc[((size_t)b * C + c) * 3 + 1];
    float S2 = Sacc[((size_t)b * C + c) * 3 + 2];
    float pm = S1 / S0;
    float var = S2 / S0 - pm * pm;
    out[(size_t)b * 2 * C + c] = pm;
    out[(size_t)b * 2 * C + C + c] = sqrtf(fmaxf(var, EPSF));
  }
}

extern "C" void kernel_launch(void* const* d_in, const int* in_sizes, int n_in,
                              void* d_out, int out_size, void* d_ws, size_t ws_size,
                              hipStream_t stream) {
  const float* x = (const float*)d_in[0];
  const float* attn_w = (const float*)d_in[1];
  const float* attn_b = (const float*)d_in[2];
  const float* ctx_w = (const float*)d_in[3];
  const int* mask = (const int*)d_in[5];
  float* out = (float*)d_out;

  int D = in_sizes[2];         // 128
  int C = in_sizes[4];         // 512
  int B = out_size / (2 * C);  // 32
  int T = in_sizes[5] / B;     // 2000

  // workspace layout (~17 MB; xbT eliminated -> x+alphaT working set is L3-resident)
  unsigned short* awb = (unsigned short*)d_ws;        // D*C bf16
  unsigned short* cwb = awb + (size_t)D * C;          // C*D bf16
  float* mean = (float*)(cwb + (size_t)C * D);        // B*C
  float* stdv = mean + (size_t)B * C;                 // B*C
  float* bias2 = stdv + (size_t)B * C;                // B*D
  float* sums = bias2 + (size_t)B * D;                // B*C*2 (zeroed)
  float* Sacc = sums + (size_t)B * C * 2;             // B*C*3 (zeroed)
  unsigned short* alphaT = (unsigned short*)(Sacc + (size_t)B * C * 3);  // B*T*D bf16

  int nzero4 = (B * C * 5 + 3) / 4;  // sums + Sacc, in float4 units
  k_zero<<<(nzero4 + 255) / 256, 256, 0, stream>>>(sums, nzero4);
  k_convert<<<(2 * D * C + 255) / 256, 256, 0, stream>>>(attn_w, ctx_w, awb, cwb, C, D);
  k_ms<<<dim3(C / 64, (T + 63) / 64, B), 256, 0, stream>>>(x, mask, sums, C, T);
  k_ms_fin<<<B, 256, 0, stream>>>(sums, mask, mean, stdv, C, T);
  k_bias2<<<B * D, 256, 0, stream>>>(attn_w, attn_b, mean, stdv, bias2, C, D);
  k_gemm1x<<<dim3((T + 63) / 64, B), 256, 0, stream>>>(x, awb, bias2, alphaT, C, T, D);
  k_pool2<<<dim3((T + 255) / 256, C / 64, B), 256, 0, stream>>>(
      alphaT, cwb, x, mask, Sacc, C, T, D);
  k_out<<<B, 256, 0, stream>>>(Sacc, out, C);
}

// Round 13
// 145.761 us; speedup vs baseline: 1.1548x; 1.1548x over previous
//
#include <hip/hip_runtime.h>
#include <hip/hip_bf16.h>
#include <math.h>

#define EPSF 1e-8f
typedef __attribute__((ext_vector_type(8))) short short8;
typedef __attribute__((ext_vector_type(4))) short s4v;
typedef __attribute__((ext_vector_type(4))) float f32x4;

__device__ __forceinline__ float wred_sum(float v) {
#pragma unroll
  for (int o = 32; o > 0; o >>= 1) v += __shfl_down(v, o, 64);
  return v;
}

static __device__ __forceinline__ unsigned short f2bf(float f) {
  __hip_bfloat16 h = __float2bfloat16(f);
  return *reinterpret_cast<unsigned short*>(&h);
}
static __device__ __forceinline__ float bf2f(unsigned short u) {
  unsigned int v = ((unsigned int)u) << 16;
  float f;
  __builtin_memcpy(&f, &v, 4);
  return f;
}

// ---------------- K-1: zero the atomic accumulators
__global__ __launch_bounds__(256) void k_zero(float* __restrict__ p, int n4) {
  int i = blockIdx.x * 256 + threadIdx.x;
  if (i < n4)
    *reinterpret_cast<float4*>(p + (size_t)i * 4) = (float4){0.f, 0.f, 0.f, 0.f};
}

// ---------------- K0: weights -> bf16 (awb[d][c] from attn_w[:, :C]; cwb = ctx_w)
__global__ __launch_bounds__(256) void k_convert(
    const float* __restrict__ attn_w, const float* __restrict__ ctx_w,
    unsigned short* __restrict__ awb, unsigned short* __restrict__ cwb, int C, int D) {
  int i = blockIdx.x * 256 + threadIdx.x;
  int DC = D * C;
  if (i < DC) {
    int d = i / C, c = i % C;
    awb[i] = f2bf(attn_w[(size_t)d * 3 * C + c]);
  } else if (i < 2 * DC) {
    int j = i - DC;
    cwb[j] = f2bf(ctx_w[j]);
  }
}

// ---------------- K1: t-tiled masked partial sums + transpose x -> xbT[b][t][c] bf16
__global__ __launch_bounds__(256) void k_ms_tr(
    const float* __restrict__ x, const int* __restrict__ mask,
    float* __restrict__ sums, unsigned short* __restrict__ xbT, int C, int T) {
  int b = blockIdx.z, c0 = blockIdx.x * 64, t0 = blockIdx.y * 64;
  int tid = threadIdx.x;
  int row = tid >> 2, q = tid & 3;
  __shared__ float Xs[64][65];
  const float* xr = x + ((size_t)b * C + c0 + row) * T;
  const int* mr = mask + (size_t)b * T;
  float s1 = 0.f, s2 = 0.f;

#pragma unroll
  for (int ss = 0; ss < 4; ss++) {
    int cc = q + 4 * ss;
    int t = t0 + cc * 4;
    float4 v;
    float mv[4];
    if (t + 3 < T) {
      v = *reinterpret_cast<const float4*>(&xr[t]);
      int4 mm = *reinterpret_cast<const int4*>(&mr[t]);
      mv[0] = (float)mm.x; mv[1] = (float)mm.y; mv[2] = (float)mm.z; mv[3] = (float)mm.w;
    } else {
      v.x = (t < T) ? xr[t] : 0.f;     mv[0] = (t < T) ? (float)mr[t] : 0.f;
      v.y = (t+1 < T) ? xr[t+1] : 0.f; mv[1] = (t+1 < T) ? (float)mr[t+1] : 0.f;
      v.z = (t+2 < T) ? xr[t+2] : 0.f; mv[2] = (t+2 < T) ? (float)mr[t+2] : 0.f;
      v.w = (t+3 < T) ? xr[t+3] : 0.f; mv[3] = (t+3 < T) ? (float)mr[t+3] : 0.f;
    }
    s1 += mv[0]*v.x + mv[1]*v.y + mv[2]*v.z + mv[3]*v.w;
    s2 += mv[0]*v.x*v.x + mv[1]*v.y*v.y + mv[2]*v.z*v.z + mv[3]*v.w*v.w;
    int tl = cc * 4;
    Xs[row][tl+0] = v.x; Xs[row][tl+1] = v.y; Xs[row][tl+2] = v.z; Xs[row][tl+3] = v.w;
  }
  __syncthreads();
  {
    int trow = tid >> 2;
    int t = t0 + trow;
    if (t < T) {
      unsigned short buf[16];
#pragma unroll
      for (int m = 0; m < 16; m++) buf[m] = f2bf(Xs[q * 16 + m][trow]);
      unsigned short* dst = &xbT[((size_t)b * T + t) * C + c0 + q * 16];
      *reinterpret_cast<short8*>(dst) = *reinterpret_cast<short8*>(&buf[0]);
      *reinterpret_cast<short8*>(dst + 8) = *reinterpret_cast<short8*>(&buf[8]);
    }
  }
  s1 += __shfl_down(s1, 2, 4); s1 += __shfl_down(s1, 1, 4);
  s2 += __shfl_down(s2, 2, 4); s2 += __shfl_down(s2, 1, 4);
  if (q == 0) {
    float* sp = &sums[((size_t)b * C + c0 + row) * 2];
    atomicAdd(sp, s1);
    atomicAdd(sp + 1, s2);
  }
}

// ---------------- K1b: finalize mean/std from sums + mask lengths
__global__ __launch_bounds__(256) void k_ms_fin(
    const float* __restrict__ sums, const int* __restrict__ mask,
    float* __restrict__ mean, float* __restrict__ stdv, int C, int T) {
  int b = blockIdx.x;
  int tid = threadIdx.x;
  const int* mr = mask + (size_t)b * T;
  float sl = 0.f;
  for (int t = tid; t < T; t += 256) sl += (float)mr[t];
  __shared__ float rl[4];
  sl = wred_sum(sl);
  if ((tid & 63) == 0) rl[tid >> 6] = sl;
  __syncthreads();
  float L = fmaxf(rl[0] + rl[1] + rl[2] + rl[3], 1.f);
  for (int c = tid; c < C; c += 256) {
    float s1 = sums[((size_t)b * C + c) * 2];
    float s2 = sums[((size_t)b * C + c) * 2 + 1];
    float mu = s1 / L;
    float var = s2 / L - mu * mu;
    mean[(size_t)b * C + c] = mu;
    stdv[(size_t)b * C + c] = sqrtf(fmaxf(var, EPSF));
  }
}

// ---------------- K2: bias2[b,d] = attn_b[d] + w[d,C:2C].mean + w[d,2C:3C].std (fp32)
__global__ __launch_bounds__(256) void k_bias2(
    const float* __restrict__ attn_w, const float* __restrict__ attn_b,
    const float* __restrict__ mean, const float* __restrict__ stdv,
    float* __restrict__ bias2, int C, int D) {
  int bd = blockIdx.x;
  int b = bd / D;
  int d = bd % D;
  const float* wr = attn_w + (size_t)d * 3 * C;
  float s = 0.f;
  for (int c = threadIdx.x; c < C; c += 256)
    s += wr[C + c] * mean[(size_t)b * C + c] + wr[2 * C + c] * stdv[(size_t)b * C + c];
  __shared__ float r[4];
  s = wred_sum(s);
  if ((threadIdx.x & 63) == 0) r[threadIdx.x >> 6] = s;
  __syncthreads();
  if (threadIdx.x == 0) bias2[bd] = attn_b[d] + r[0] + r[1] + r[2] + r[3];
}

// ---------------- K3: MFMA GEMM1 -> alphaT[b][t][d] = tanh(bias2 + sum_c xbT*awb)
// K-loop register-prefetch pipeline (validated round 7/8/11).
__global__ __launch_bounds__(256) void k_gemm1(
    const unsigned short* __restrict__ xbT, const unsigned short* __restrict__ awb,
    const float* __restrict__ bias2, unsigned short* __restrict__ alphaT,
    int C, int T, int D) {
  int b = blockIdx.y;
  int t0 = blockIdx.x * 128;
  int tid = threadIdx.x;
  int w = tid >> 6, lane = tid & 63;
  int wt0 = (w >> 1) * 64, wd0 = (w & 1) * 64;
  int l15 = lane & 15, g = lane >> 4;
  __shared__ unsigned short As[128][72];  // [t][c] pitch 144B
  __shared__ unsigned short Bs[128][72];  // [d][c]
  f32x4 acc[4][4];
#pragma unroll
  for (int i = 0; i < 4; i++)
#pragma unroll
    for (int j = 0; j < 4; j++) acc[i][j] = (f32x4){0.f, 0.f, 0.f, 0.f};

  int srow = tid >> 1, h = tid & 1;
  bool okA = (t0 + srow) < T;
  size_t rowA = ((size_t)b * T + t0 + srow) * C + h * 32;
  size_t rowB = (size_t)srow * C + h * 32;

  short8 ra[4], rb[4];
#pragma unroll
  for (int qq = 0; qq < 4; qq++) {
    ra[qq] = okA ? *reinterpret_cast<const short8*>(&xbT[rowA + qq * 8]) : (short8){};
    rb[qq] = *reinterpret_cast<const short8*>(&awb[rowB + qq * 8]);
  }

  for (int c0 = 0; c0 < C; c0 += 64) {
    __syncthreads();
#pragma unroll
    for (int qq = 0; qq < 4; qq++) {
      *reinterpret_cast<short8*>(&As[srow][h * 32 + qq * 8]) = ra[qq];
      *reinterpret_cast<short8*>(&Bs[srow][h * 32 + qq * 8]) = rb[qq];
    }
    if (c0 + 64 < C) {
      size_t nA = rowA + c0 + 64, nB = rowB + c0 + 64;
#pragma unroll
      for (int qq = 0; qq < 4; qq++) {
        ra[qq] = okA ? *reinterpret_cast<const short8*>(&xbT[nA + qq * 8]) : (short8){};
        rb[qq] = *reinterpret_cast<const short8*>(&awb[nB + qq * 8]);
      }
    }
    __syncthreads();
#pragma unroll
    for (int ks = 0; ks < 2; ks++) {
      short8 a[4], bb[4];
#pragma unroll
      for (int tf = 0; tf < 4; tf++)
        a[tf] = *reinterpret_cast<const short8*>(&As[wt0 + tf * 16 + l15][ks * 32 + g * 8]);
#pragma unroll
      for (int df = 0; df < 4; df++)
        bb[df] = *reinterpret_cast<const short8*>(&Bs[wd0 + df * 16 + l15][ks * 32 + g * 8]);
#pragma unroll
      for (int tf = 0; tf < 4; tf++)
#pragma unroll
        for (int df = 0; df < 4; df++)
          acc[tf][df] = __builtin_amdgcn_mfma_f32_16x16x32_bf16(a[tf], bb[df], acc[tf][df], 0, 0, 0);
    }
  }
#pragma unroll
  for (int df = 0; df < 4; df++) {
    int d = wd0 + df * 16 + l15;
    float bias = bias2[(size_t)b * D + d];
#pragma unroll
    for (int tf = 0; tf < 4; tf++)
#pragma unroll
      for (int r = 0; r < 4; r++) {
        int t = t0 + wt0 + tf * 16 + g * 4 + r;
        if (t < T)
          alphaT[((size_t)b * T + t) * D + d] = f2bf(tanhf(bias + acc[tf][df][r]));
      }
  }
}

// ---------------- K4: fused MFMA GEMM2 + masked exp + partial pooled sums
// r11's depth-2 Bl pipeline, with the x-LDS tile DELETED: each lane's 4 xv
// values are contiguous in xbT ([t][c] layout), so one 8B global gather per
// t-frag replaces the whole Xt staging path (LDS 53->34.8 KB -> 4 blocks/CU,
// 2 fewer loads in the vmcnt chain, no ds_read_u16). Gathers are L2-served:
// each 128B xbT line is fully consumed by the block's 4 waves.
// ctx_b omitted (softmax shift-invariance).
__global__ __launch_bounds__(256) void k_pool2(
    const unsigned short* __restrict__ alphaT, const unsigned short* __restrict__ cwb,
    const unsigned short* __restrict__ xbT, const int* __restrict__ mask,
    float* __restrict__ Sacc, int C, int T, int D) {
  int b = blockIdx.z;
  int c0 = blockIdx.y * 64;
  int ch0 = blockIdx.x * 256;
  int tid = threadIdx.x;
  int w = tid >> 6, lane = tid & 63, l15 = lane & 15, g = lane >> 4;
  __shared__ unsigned short Bl[2][64][136];  // alphaT tiles [t][d]

  // ctx_w fragments (L2-resident, 128 KB)
  short8 a[4];
#pragma unroll
  for (int ks = 0; ks < 4; ks++)
    a[ks] = *reinterpret_cast<const short8*>(
        &cwb[(size_t)(c0 + w * 16 + l15) * D + ks * 32 + g * 8]);
  int cbase = c0 + w * 16 + g * 4;
  float S0[4] = {0.f, 0.f, 0.f, 0.f};
  float S1[4] = {0.f, 0.f, 0.f, 0.f};
  float S2[4] = {0.f, 0.f, 0.f, 0.f};

  const int* mr = mask + (size_t)b * T;
  int srow = tid >> 2, sq = tid & 3;

  int rem = T - ch0;
  int ntt = rem >= 256 ? 4 : (rem + 63) >> 6;

  short8 pa0, pa1, pa2, pa3;

#define LOADSUB(st)                                                            \
  {                                                                            \
    int trow = ch0 + (st) * 64 + srow;                                         \
    pa0 = pa1 = pa2 = pa3 = (short8){};                                        \
    if (trow < T) {                                                            \
      const unsigned short* sa = &alphaT[((size_t)b * T + trow) * D + sq * 32];\
      pa0 = *reinterpret_cast<const short8*>(sa);                              \
      pa1 = *reinterpret_cast<const short8*>(sa + 8);                          \
      pa2 = *reinterpret_cast<const short8*>(sa + 16);                         \
      pa3 = *reinterpret_cast<const short8*>(sa + 24);                         \
    }                                                                          \
  }

#define WRITESUB(bufi)                                                         \
  {                                                                            \
    *reinterpret_cast<short8*>(&Bl[bufi][srow][sq * 32]) = pa0;                \
    *reinterpret_cast<short8*>(&Bl[bufi][srow][sq * 32 + 8]) = pa1;            \
    *reinterpret_cast<short8*>(&Bl[bufi][srow][sq * 32 + 16]) = pa2;           \
    *reinterpret_cast<short8*>(&Bl[bufi][srow][sq * 32 + 24]) = pa3;           \
  }

  // prologue: buf0 <- subtile 0; regs <- subtile 1
  LOADSUB(0);
  WRITESUB(0);
  if (ntt > 1) LOADSUB(1);
  __syncthreads();  // buf0 visible

  for (int k = 0; k < ntt; k++) {
    int buf = k & 1;
    if (k + 1 < ntt) {
      WRITESUB((k + 1) & 1);            // waits on loads issued at iter k-1
      if (k + 2 < ntt) LOADSUB(k + 2);  // in flight through next compute
    }
    int t0 = ch0 + k * 64;
    // direct xv gathers for this subtile (independent; hoisted ahead of MFMAs)
    s4v xv4[4];
#pragma unroll
    for (int tf = 0; tf < 4; tf++) {
      int t = t0 + tf * 16 + l15;
      int tc = t < T ? t : T - 1;  // clamped: in-bounds, real data
      xv4[tf] = *reinterpret_cast<const s4v*>(&xbT[((size_t)b * T + tc) * C + cbase]);
    }
#pragma unroll
    for (int tf = 0; tf < 4; tf++) {
      f32x4 p = (f32x4){0.f, 0.f, 0.f, 0.f};
#pragma unroll
      for (int ks = 0; ks < 4; ks++) {
        short8 bb = *reinterpret_cast<const short8*>(
            &Bl[buf][tf * 16 + l15][ks * 32 + g * 8]);
        p = __builtin_amdgcn_mfma_f32_16x16x32_bf16(a[ks], bb, p, 0, 0, 0);
      }
      int t = t0 + tf * 16 + l15;
      bool valid = (t < T) && (mr[t < T ? t : 0] != 0);
#pragma unroll
      for (int r = 0; r < 4; r++) {
        float e = valid ? __expf(p[r]) : 0.f;  // logits tanh-bounded: no max-sub
        float xv = bf2f((unsigned short)xv4[tf][r]);
        S0[r] += e; S1[r] += e * xv; S2[r] += e * xv * xv;
      }
    }
    __syncthreads();  // compute(k) done before buf gets overwritten at k+1
  }
#undef LOADSUB
#undef WRITESUB

#pragma unroll
  for (int r = 0; r < 4; r++) {
#pragma unroll
    for (int o = 1; o < 16; o <<= 1) {
      S0[r] += __shfl_xor(S0[r], o, 16);
      S1[r] += __shfl_xor(S1[r], o, 16);
      S2[r] += __shfl_xor(S2[r], o, 16);
    }
  }
  if (l15 == 0) {
#pragma unroll
    for (int r = 0; r < 4; r++) {
      float* sp = &Sacc[((size_t)b * C + cbase + r) * 3];
      atomicAdd(sp, S0[r]);
      atomicAdd(sp + 1, S1[r]);
      atomicAdd(sp + 2, S2[r]);
    }
  }
}

// ---------------- K5: finalize pooled mean/std
__global__ __launch_bounds__(256) void k_out(
    const float* __restrict__ Sacc, float* __restrict__ out, int C) {
  int b = blockIdx.x;
  for (int c = threadIdx.x; c < C; c += 256) {
    float S0 = Sacc[((size_t)b * C + c) * 3];
    float S1 = Sacc[((size_t)b * C + c) * 3 + 1];
    float S2 = Sacc[((size_t)b * C + c) * 3 + 2];
    float pm = S1 / S0;
    float var = S2 / S0 - pm * pm;
    out[(size_t)b * 2 * C + c] = pm;
    out[(size_t)b * 2 * C + C + c] = sqrtf(fmaxf(var, EPSF));
  }
}

extern "C" void kernel_launch(void* const* d_in, const int* in_sizes, int n_in,
                              void* d_out, int out_size, void* d_ws, size_t ws_size,
                              hipStream_t stream) {
  const float* x = (const float*)d_in[0];
  const float* attn_w = (const float*)d_in[1];
  const float* attn_b = (const float*)d_in[2];
  const float* ctx_w = (const float*)d_in[3];
  const int* mask = (const int*)d_in[5];
  float* out = (float*)d_out;

  int D = in_sizes[2];         // 128
  int C = in_sizes[4];         // 512
  int B = out_size / (2 * C);  // 32
  int T = in_sizes[5] / B;     // 2000

  // workspace layout (~82.7 MB)
  unsigned short* awb = (unsigned short*)d_ws;        // D*C bf16
  unsigned short* cwb = awb + (size_t)D * C;          // C*D bf16
  float* mean = (float*)(cwb + (size_t)C * D);        // B*C
  float* stdv = mean + (size_t)B * C;                 // B*C
  float* bias2 = stdv + (size_t)B * C;                // B*D
  float* sums = bias2 + (size_t)B * D;                // B*C*2 (zeroed)
  float* Sacc = sums + (size_t)B * C * 2;             // B*C*3 (zeroed)
  unsigned short* xbT = (unsigned short*)(Sacc + (size_t)B * C * 3);  // B*T*C bf16
  unsigned short* alphaT = xbT + (size_t)B * T * C;                   // B*T*D bf16

  int nzero4 = (B * C * 5 + 3) / 4;  // sums + Sacc, in float4 units
  k_zero<<<(nzero4 + 255) / 256, 256, 0, stream>>>(sums, nzero4);
  k_convert<<<(2 * D * C + 255) / 256, 256, 0, stream>>>(attn_w, ctx_w, awb, cwb, C, D);
  k_ms_tr<<<dim3(C / 64, (T + 63) / 64, B), 256, 0, stream>>>(x, mask, sums, xbT, C, T);
  k_ms_fin<<<B, 256, 0, stream>>>(sums, mask, mean, stdv, C, T);
  k_bias2<<<B * D, 256, 0, stream>>>(attn_w, attn_b, mean, stdv, bias2, C, D);
  k_gemm1<<<dim3((T + 127) / 128, B), 256, 0, stream>>>(xbT, awb, bias2, alphaT, C, T, D);
  k_pool2<<<dim3((T + 255) / 256, C / 64, B), 256, 0, stream>>>(
      alphaT, cwb, xbT, mask, Sacc, C, T, D);
  k_out<<<B, 256, 0, stream>>>(Sacc, out, C);
}

// Round 14
// 133.122 us; speedup vs baseline: 1.2645x; 1.0949x over previous
//
#include <hip/hip_runtime.h>
#include <hip/hip_bf16.h>
#include <math.h>

#define EPSF 1e-8f
typedef __attribute__((ext_vector_type(8))) short short8;
typedef __attribute__((ext_vector_type(4))) float f32x4;

__device__ __forceinline__ float wred_sum(float v) {
#pragma unroll
  for (int o = 32; o > 0; o >>= 1) v += __shfl_down(v, o, 64);
  return v;
}

static __device__ __forceinline__ unsigned short f2bf(float f) {
  __hip_bfloat16 h = __float2bfloat16(f);
  return *reinterpret_cast<unsigned short*>(&h);
}
static __device__ __forceinline__ float bf2f(unsigned short u) {
  unsigned int v = ((unsigned int)u) << 16;
  float f;
  __builtin_memcpy(&f, &v, 4);
  return f;
}

// ---------------- K0: merged {zero accumulators + weights->bf16}
__global__ __launch_bounds__(256) void k_zc(
    const float* __restrict__ attn_w, const float* __restrict__ ctx_w,
    unsigned short* __restrict__ awb, unsigned short* __restrict__ cwb,
    float* __restrict__ zp, int nz4, int C, int D) {
  int i = blockIdx.x * 256 + threadIdx.x;
  int DC = D * C;
  if (i < DC) {
    int d = i / C, c = i % C;
    awb[i] = f2bf(attn_w[(size_t)d * 3 * C + c]);
  } else if (i < 2 * DC) {
    int j = i - DC;
    cwb[j] = f2bf(ctx_w[j]);
  }
  if (i < nz4)
    *reinterpret_cast<float4*>(zp + (size_t)i * 4) = (float4){0.f, 0.f, 0.f, 0.f};
}

// ---------------- K1: t-tiled masked partial sums + transpose x -> xbT[b][t][c] bf16
__global__ __launch_bounds__(256) void k_ms_tr(
    const float* __restrict__ x, const int* __restrict__ mask,
    float* __restrict__ sums, unsigned short* __restrict__ xbT, int C, int T) {
  int b = blockIdx.z, c0 = blockIdx.x * 64, t0 = blockIdx.y * 64;
  int tid = threadIdx.x;
  int row = tid >> 2, q = tid & 3;
  __shared__ float Xs[64][65];
  const float* xr = x + ((size_t)b * C + c0 + row) * T;
  const int* mr = mask + (size_t)b * T;
  float s1 = 0.f, s2 = 0.f;

#pragma unroll
  for (int ss = 0; ss < 4; ss++) {
    int cc = q + 4 * ss;
    int t = t0 + cc * 4;
    float4 v;
    float mv[4];
    if (t + 3 < T) {
      v = *reinterpret_cast<const float4*>(&xr[t]);
      int4 mm = *reinterpret_cast<const int4*>(&mr[t]);
      mv[0] = (float)mm.x; mv[1] = (float)mm.y; mv[2] = (float)mm.z; mv[3] = (float)mm.w;
    } else {
      v.x = (t < T) ? xr[t] : 0.f;     mv[0] = (t < T) ? (float)mr[t] : 0.f;
      v.y = (t+1 < T) ? xr[t+1] : 0.f; mv[1] = (t+1 < T) ? (float)mr[t+1] : 0.f;
      v.z = (t+2 < T) ? xr[t+2] : 0.f; mv[2] = (t+2 < T) ? (float)mr[t+2] : 0.f;
      v.w = (t+3 < T) ? xr[t+3] : 0.f; mv[3] = (t+3 < T) ? (float)mr[t+3] : 0.f;
    }
    s1 += mv[0]*v.x + mv[1]*v.y + mv[2]*v.z + mv[3]*v.w;
    s2 += mv[0]*v.x*v.x + mv[1]*v.y*v.y + mv[2]*v.z*v.z + mv[3]*v.w*v.w;
    int tl = cc * 4;
    Xs[row][tl+0] = v.x; Xs[row][tl+1] = v.y; Xs[row][tl+2] = v.z; Xs[row][tl+3] = v.w;
  }
  __syncthreads();
  {
    int trow = tid >> 2;
    int t = t0 + trow;
    if (t < T) {
      unsigned short buf[16];
#pragma unroll
      for (int m = 0; m < 16; m++) buf[m] = f2bf(Xs[q * 16 + m][trow]);
      unsigned short* dst = &xbT[((size_t)b * T + t) * C + c0 + q * 16];
      *reinterpret_cast<short8*>(dst) = *reinterpret_cast<short8*>(&buf[0]);
      *reinterpret_cast<short8*>(dst + 8) = *reinterpret_cast<short8*>(&buf[8]);
    }
  }
  s1 += __shfl_down(s1, 2, 4); s1 += __shfl_down(s1, 1, 4);
  s2 += __shfl_down(s2, 2, 4); s2 += __shfl_down(s2, 1, 4);
  if (q == 0) {
    float* sp = &sums[((size_t)b * C + c0 + row) * 2];
    atomicAdd(sp, s1);
    atomicAdd(sp + 1, s2);
  }
}

// ---------------- K2: merged {mask length + mean/std from sums + bias2 dot}
// bias2[b,d] = attn_b[d] + w[d,C:2C].mean + w[d,2C:3C].std  (all fp32,
// bitwise-identical formulas/order to the former k_ms_fin + k_bias2 pair)
__global__ __launch_bounds__(256) void k_bias2f(
    const float* __restrict__ attn_w, const float* __restrict__ attn_b,
    const float* __restrict__ sums, const int* __restrict__ mask,
    float* __restrict__ bias2, int C, int D, int T) {
  int bd = blockIdx.x;
  int b = bd / D;
  int d = bd % D;
  int tid = threadIdx.x;
  const int* mr = mask + (size_t)b * T;
  float sl = 0.f;
  for (int t = tid; t < T; t += 256) sl += (float)mr[t];
  __shared__ float rl[4];
  sl = wred_sum(sl);
  if ((tid & 63) == 0) rl[tid >> 6] = sl;
  __syncthreads();
  float L = fmaxf(rl[0] + rl[1] + rl[2] + rl[3], 1.f);

  const float* wr = attn_w + (size_t)d * 3 * C;
  float s = 0.f;
  for (int c = tid; c < C; c += 256) {
    float s1 = sums[((size_t)b * C + c) * 2];
    float s2 = sums[((size_t)b * C + c) * 2 + 1];
    float mu = s1 / L;
    float var = s2 / L - mu * mu;
    float sd = sqrtf(fmaxf(var, EPSF));
    s += wr[C + c] * mu + wr[2 * C + c] * sd;
  }
  __shared__ float r[4];
  s = wred_sum(s);
  if ((tid & 63) == 0) r[tid >> 6] = s;
  __syncthreads();
  if (tid == 0) bias2[bd] = attn_b[d] + r[0] + r[1] + r[2] + r[3];
}

// ---------------- K3: MFMA GEMM1, 64t x 128d tile (grid 1024 = 4 blocks/CU;
// the old 128t tile gave only 512 blocks = 2/CU, grid-capped occupancy 21%).
// K-chunk 64, register-prefetched. Same fragment formulas (wt0=0, wd0=w*32).
__global__ __launch_bounds__(256) void k_gemm1(
    const unsigned short* __restrict__ xbT, const unsigned short* __restrict__ awb,
    const float* __restrict__ bias2, unsigned short* __restrict__ alphaT,
    int C, int T, int D) {
  int b = blockIdx.y;
  int t0 = blockIdx.x * 64;
  int tid = threadIdx.x;
  int w = tid >> 6, lane = tid & 63;
  int l15 = lane & 15, g = lane >> 4;
  __shared__ unsigned short As[64][72];   // [t][c] pitch 144B
  __shared__ unsigned short Bs[128][72];  // [d][c]
  f32x4 acc[4][2];
#pragma unroll
  for (int i = 0; i < 4; i++)
#pragma unroll
    for (int j = 0; j < 2; j++) acc[i][j] = (f32x4){0.f, 0.f, 0.f, 0.f};

  int ar = tid >> 2, aq = tid & 3;  // A staging: t-row, 16-short quarter
  int dr = tid >> 1, h = tid & 1;   // B staging: d-row, 32-short half
  bool okA = (t0 + ar) < T;
  size_t rowA = ((size_t)b * T + t0 + ar) * C + aq * 16;
  size_t rowB = (size_t)dr * C + h * 32;

  short8 ra[2], rb[4];
  ra[0] = okA ? *reinterpret_cast<const short8*>(&xbT[rowA]) : (short8){};
  ra[1] = okA ? *reinterpret_cast<const short8*>(&xbT[rowA + 8]) : (short8){};
#pragma unroll
  for (int qq = 0; qq < 4; qq++)
    rb[qq] = *reinterpret_cast<const short8*>(&awb[rowB + qq * 8]);

  for (int c0 = 0; c0 < C; c0 += 64) {
    __syncthreads();
    *reinterpret_cast<short8*>(&As[ar][aq * 16]) = ra[0];
    *reinterpret_cast<short8*>(&As[ar][aq * 16 + 8]) = ra[1];
#pragma unroll
    for (int qq = 0; qq < 4; qq++)
      *reinterpret_cast<short8*>(&Bs[dr][h * 32 + qq * 8]) = rb[qq];
    if (c0 + 64 < C) {
      size_t nA = rowA + c0 + 64, nB = rowB + c0 + 64;
      ra[0] = okA ? *reinterpret_cast<const short8*>(&xbT[nA]) : (short8){};
      ra[1] = okA ? *reinterpret_cast<const short8*>(&xbT[nA + 8]) : (short8){};
#pragma unroll
      for (int qq = 0; qq < 4; qq++)
        rb[qq] = *reinterpret_cast<const short8*>(&awb[nB + qq * 8]);
    }
    __syncthreads();
#pragma unroll
    for (int ks = 0; ks < 2; ks++) {
      short8 a[4], bb[2];
#pragma unroll
      for (int tf = 0; tf < 4; tf++)
        a[tf] = *reinterpret_cast<const short8*>(&As[tf * 16 + l15][ks * 32 + g * 8]);
#pragma unroll
      for (int df = 0; df < 2; df++)
        bb[df] = *reinterpret_cast<const short8*>(&Bs[w * 32 + df * 16 + l15][ks * 32 + g * 8]);
#pragma unroll
      for (int tf = 0; tf < 4; tf++)
#pragma unroll
        for (int df = 0; df < 2; df++)
          acc[tf][df] = __builtin_amdgcn_mfma_f32_16x16x32_bf16(a[tf], bb[df], acc[tf][df], 0, 0, 0);
    }
  }
#pragma unroll
  for (int df = 0; df < 2; df++) {
    int d = w * 32 + df * 16 + l15;
    float bias = bias2[(size_t)b * D + d];
#pragma unroll
    for (int tf = 0; tf < 4; tf++)
#pragma unroll
      for (int r = 0; r < 4; r++) {
        int t = t0 + tf * 16 + g * 4 + r;
        if (t < T)
          alphaT[((size_t)b * T + t) * D + d] = f2bf(tanhf(bias + acc[tf][df][r]));
      }
  }
}

// ---------------- K4: fused MFMA GEMM2 + masked exp + partial pooled sums
// r11's validated depth-2 pipeline (best measured config: 142.9 total).
// ctx_b omitted (softmax shift-invariance).
__global__ __launch_bounds__(256) void k_pool2(
    const unsigned short* __restrict__ alphaT, const unsigned short* __restrict__ cwb,
    const unsigned short* __restrict__ xbT, const int* __restrict__ mask,
    float* __restrict__ Sacc, int C, int T, int D) {
  int b = blockIdx.z;
  int c0 = blockIdx.y * 64;
  int ch0 = blockIdx.x * 256;
  int tid = threadIdx.x;
  int w = tid >> 6, lane = tid & 63, l15 = lane & 15, g = lane >> 4;
  __shared__ unsigned short Bl[2][64][136];  // alphaT tiles [t][d]
  __shared__ unsigned short Xt[2][64][72];   // xbT tiles [t][c-local]

  short8 a[4];
#pragma unroll
  for (int ks = 0; ks < 4; ks++)
    a[ks] = *reinterpret_cast<const short8*>(
        &cwb[(size_t)(c0 + w * 16 + l15) * D + ks * 32 + g * 8]);
  int cbase = c0 + w * 16 + g * 4;
  float S0[4] = {0.f, 0.f, 0.f, 0.f};
  float S1[4] = {0.f, 0.f, 0.f, 0.f};
  float S2[4] = {0.f, 0.f, 0.f, 0.f};

  const int* mr = mask + (size_t)b * T;
  int srow = tid >> 2, sq = tid & 3;

  int rem = T - ch0;
  int ntt = rem >= 256 ? 4 : (rem + 63) >> 6;

  short8 pa0, pa1, pa2, pa3, px0, px1;

#define LOADSUB(st)                                                            \
  {                                                                            \
    int trow = ch0 + (st) * 64 + srow;                                         \
    pa0 = pa1 = pa2 = pa3 = px0 = px1 = (short8){};                            \
    if (trow < T) {                                                            \
      const unsigned short* sa = &alphaT[((size_t)b * T + trow) * D + sq * 32];\
      pa0 = *reinterpret_cast<const short8*>(sa);                              \
      pa1 = *reinterpret_cast<const short8*>(sa + 8);                          \
      pa2 = *reinterpret_cast<const short8*>(sa + 16);                         \
      pa3 = *reinterpret_cast<const short8*>(sa + 24);                         \
      const unsigned short* sx = &xbT[((size_t)b * T + trow) * C + c0 + sq*16];\
      px0 = *reinterpret_cast<const short8*>(sx);                              \
      px1 = *reinterpret_cast<const short8*>(sx + 8);                          \
    }                                                                          \
  }

#define WRITESUB(bufi)                                                         \
  {                                                                            \
    *reinterpret_cast<short8*>(&Bl[bufi][srow][sq * 32]) = pa0;                \
    *reinterpret_cast<short8*>(&Bl[bufi][srow][sq * 32 + 8]) = pa1;            \
    *reinterpret_cast<short8*>(&Bl[bufi][srow][sq * 32 + 16]) = pa2;           \
    *reinterpret_cast<short8*>(&Bl[bufi][srow][sq * 32 + 24]) = pa3;           \
    *reinterpret_cast<short8*>(&Xt[bufi][srow][sq * 16]) = px0;                \
    *reinterpret_cast<short8*>(&Xt[bufi][srow][sq * 16 + 8]) = px1;            \
  }

  LOADSUB(0);
  WRITESUB(0);
  if (ntt > 1) LOADSUB(1);
  __syncthreads();

  for (int k = 0; k < ntt; k++) {
    int buf = k & 1;
    if (k + 1 < ntt) {
      WRITESUB((k + 1) & 1);
      if (k + 2 < ntt) LOADSUB(k + 2);
    }
    int t0 = ch0 + k * 64;
#pragma unroll
    for (int tf = 0; tf < 4; tf++) {
      f32x4 p = (f32x4){0.f, 0.f, 0.f, 0.f};
#pragma unroll
      for (int ks = 0; ks < 4; ks++) {
        short8 bb = *reinterpret_cast<const short8*>(
            &Bl[buf][tf * 16 + l15][ks * 32 + g * 8]);
        p = __builtin_amdgcn_mfma_f32_16x16x32_bf16(a[ks], bb, p, 0, 0, 0);
      }
      int t = t0 + tf * 16 + l15;
      bool valid = (t < T) && (mr[t < T ? t : 0] != 0);
#pragma unroll
      for (int r = 0; r < 4; r++) {
        float e = valid ? __expf(p[r]) : 0.f;  // logits tanh-bounded: no max-sub
        float xv = bf2f(Xt[buf][tf * 16 + l15][w * 16 + g * 4 + r]);
        S0[r] += e; S1[r] += e * xv; S2[r] += e * xv * xv;
      }
    }
    __syncthreads();
  }
#undef LOADSUB
#undef WRITESUB

#pragma unroll
  for (int r = 0; r < 4; r++) {
#pragma unroll
    for (int o = 1; o < 16; o <<= 1) {
      S0[r] += __shfl_xor(S0[r], o, 16);
      S1[r] += __shfl_xor(S1[r], o, 16);
      S2[r] += __shfl_xor(S2[r], o, 16);
    }
  }
  if (l15 == 0) {
#pragma unroll
    for (int r = 0; r < 4; r++) {
      float* sp = &Sacc[((size_t)b * C + cbase + r) * 3];
      atomicAdd(sp, S0[r]);
      atomicAdd(sp + 1, S1[r]);
      atomicAdd(sp + 2, S2[r]);
    }
  }
}

// ---------------- K5: finalize pooled mean/std
__global__ __launch_bounds__(256) void k_out(
    const float* __restrict__ Sacc, float* __restrict__ out, int C) {
  int b = blockIdx.x;
  for (int c = threadIdx.x; c < C; c += 256) {
    float S0 = Sacc[((size_t)b * C + c) * 3];
    float S1 = Sacc[((size_t)b * C + c) * 3 + 1];
    float S2 = Sacc[((size_t)b * C + c) * 3 + 2];
    float pm = S1 / S0;
    float var = S2 / S0 - pm * pm;
    out[(size_t)b * 2 * C + c] = pm;
    out[(size_t)b * 2 * C + C + c] = sqrtf(fmaxf(var, EPSF));
  }
}

extern "C" void kernel_launch(void* const* d_in, const int* in_sizes, int n_in,
                              void* d_out, int out_size, void* d_ws, size_t ws_size,
                              hipStream_t stream) {
  const float* x = (const float*)d_in[0];
  const float* attn_w = (const float*)d_in[1];
  const float* attn_b = (const float*)d_in[2];
  const float* ctx_w = (const float*)d_in[3];
  const int* mask = (const int*)d_in[5];
  float* out = (float*)d_out;

  int D = in_sizes[2];         // 128
  int C = in_sizes[4];         // 512
  int B = out_size / (2 * C);  // 32
  int T = in_sizes[5] / B;     // 2000

  // workspace layout (~82.5 MB)
  unsigned short* awb = (unsigned short*)d_ws;        // D*C bf16
  unsigned short* cwb = awb + (size_t)D * C;          // C*D bf16
  float* bias2 = (float*)(cwb + (size_t)C * D);       // B*D
  float* sums = bias2 + (size_t)B * D;                // B*C*2 (zeroed)
  float* Sacc = sums + (size_t)B * C * 2;             // B*C*3 (zeroed)
  unsigned short* xbT = (unsigned short*)(Sacc + (size_t)B * C * 3);  // B*T*C bf16
  unsigned short* alphaT = xbT + (size_t)B * T * C;                   // B*T*D bf16

  int nz4 = (B * C * 5 + 3) / 4;  // sums + Sacc, in float4 units
  int zcn = 2 * D * C > nz4 * 0 + 2 * D * C ? 2 * D * C : nz4;  // max
  if (nz4 > zcn) zcn = nz4;
  k_zc<<<(zcn + 255) / 256, 256, 0, stream>>>(attn_w, ctx_w, awb, cwb, sums, nz4, C, D);
  k_ms_tr<<<dim3(C / 64, (T + 63) / 64, B), 256, 0, stream>>>(x, mask, sums, xbT, C, T);
  k_bias2f<<<B * D, 256, 0, stream>>>(attn_w, attn_b, sums, mask, bias2, C, D, T);
  k_gemm1<<<dim3((T + 63) / 64, B), 256, 0, stream>>>(xbT, awb, bias2, alphaT, C, T, D);
  k_pool2<<<dim3((T + 255) / 256, C / 64, B), 256, 0, stream>>>(
      alphaT, cwb, xbT, mask, Sacc, C, T, D);
  k_out<<<B, 256, 0, stream>>>(Sacc, out, C);
}